// Round 1
// baseline (4822.982 us; speedup 1.0000x reference)
//
#include <hip/hip_runtime.h>
#include <math.h>

// ULOSD keypoint autoencoder, fp32 direct convolutions.
// B=32 (4*8), encoder 7 convs -> R(32,128,16,16) -> keypoint maps -> decoder 6 layers.

enum { ACT_ID = 0, ACT_LRELU = 1, ACT_SOFTPLUS = 2, ACT_RELU = 3 };

template<int ACT>
__device__ __forceinline__ float act_fn(float x) {
  if (ACT == ACT_LRELU)    return x >= 0.f ? x : 0.2f * x;
  if (ACT == ACT_SOFTPLUS) return fmaxf(x, 0.f) + log1pf(expf(-fabsf(x)));
  if (ACT == ACT_RELU)     return fmaxf(x, 0.f);
  return x;
}

// ---------------- stride-1 3x3 SAME conv (pad 1/1). thread = 4 output cols ----
template<int ACT>
__global__ __launch_bounds__(256)
void conv3x3_s1(const float* __restrict__ in, const float* __restrict__ w,
                const float* __restrict__ bias, float* __restrict__ out,
                int Cin, int Cout, int H, int W) {
  const int plane = blockIdx.x;            // b*Cout + co
  const int co = plane % Cout;
  const int Wq = W >> 2;
  const int quads = H * Wq;
  const int item = blockIdx.y * 256 + threadIdx.x;
  if (item >= quads) return;
  const int y  = item / Wq;
  const int x0 = (item - y * Wq) << 2;

  const int HW = H * W;
  const int b = plane / Cout;
  const float* ib = in + (size_t)b * Cin * HW;
  const float* wb = w + (size_t)co * Cin * 9;

  const bool okT = (y > 0), okB = (y < H - 1);
  const bool okL = (x0 > 0), okR = (x0 + 4 < W);
  const int ymc = okT ? (y - 1) : 0;
  const int ypc = okB ? (y + 1) : 0;
  const int xl  = okL ? (x0 - 1) : 0;
  const int xr  = okR ? (x0 + 4) : 0;

  float a0 = 0.f, a1 = 0.f, a2 = 0.f, a3 = 0.f;

  for (int ci = 0; ci < Cin; ++ci) {
    const float* p = ib + ci * HW;
    const float* wp = wb + ci * 9;
    const float w00 = wp[0], w01 = wp[1], w02 = wp[2];
    const float w10 = wp[3], w11 = wp[4], w12 = wp[5];
    const float w20 = wp[6], w21 = wp[7], w22 = wp[8];
    { // top row (y-1)
      const float* r = p + ymc * W;
      float v0 = r[xl];   v0 = (okT && okL) ? v0 : 0.f;
      float v1 = r[x0], v2 = r[x0+1], v3 = r[x0+2], v4 = r[x0+3];
      if (!okT) { v1 = 0.f; v2 = 0.f; v3 = 0.f; v4 = 0.f; }
      float v5 = r[xr];   v5 = (okT && okR) ? v5 : 0.f;
      a0 += v0*w00 + v1*w01 + v2*w02;
      a1 += v1*w00 + v2*w01 + v3*w02;
      a2 += v2*w00 + v3*w01 + v4*w02;
      a3 += v3*w00 + v4*w01 + v5*w02;
    }
    { // middle row (y)
      const float* r = p + y * W;
      float v0 = r[xl];   v0 = okL ? v0 : 0.f;
      float v1 = r[x0], v2 = r[x0+1], v3 = r[x0+2], v4 = r[x0+3];
      float v5 = r[xr];   v5 = okR ? v5 : 0.f;
      a0 += v0*w10 + v1*w11 + v2*w12;
      a1 += v1*w10 + v2*w11 + v3*w12;
      a2 += v2*w10 + v3*w11 + v4*w12;
      a3 += v3*w10 + v4*w11 + v5*w12;
    }
    { // bottom row (y+1)
      const float* r = p + ypc * W;
      float v0 = r[xl];   v0 = (okB && okL) ? v0 : 0.f;
      float v1 = r[x0], v2 = r[x0+1], v3 = r[x0+2], v4 = r[x0+3];
      if (!okB) { v1 = 0.f; v2 = 0.f; v3 = 0.f; v4 = 0.f; }
      float v5 = r[xr];   v5 = (okB && okR) ? v5 : 0.f;
      a0 += v0*w20 + v1*w21 + v2*w22;
      a1 += v1*w20 + v2*w21 + v3*w22;
      a2 += v2*w20 + v3*w21 + v4*w22;
      a3 += v3*w20 + v4*w21 + v5*w22;
    }
  }

  const float bv = bias[co];
  float4 r4;
  r4.x = act_fn<ACT>(a0 + bv);
  r4.y = act_fn<ACT>(a1 + bv);
  r4.z = act_fn<ACT>(a2 + bv);
  r4.w = act_fn<ACT>(a3 + bv);
  float* op = out + (size_t)plane * HW + y * W + x0;
  *(float4*)op = r4;
}

// ---------------- stride-2 3x3 SAME conv (even in -> pad_before=0, pad_after=1) ----
template<int ACT>
__global__ __launch_bounds__(256)
void conv3x3_s2(const float* __restrict__ in, const float* __restrict__ w,
                const float* __restrict__ bias, float* __restrict__ out,
                int Cin, int Cout, int H, int W) {
  const int Ho = H >> 1, Wo = W >> 1;
  const int plane = blockIdx.x;
  const int co = plane % Cout;
  const int b  = plane / Cout;
  const int Wq = Wo >> 2;
  const int quads = Ho * Wq;
  const int item = blockIdx.y * 256 + threadIdx.x;
  if (item >= quads) return;
  const int y  = item / Wq;
  const int x0 = (item - y * Wq) << 2;   // output cols x0..x0+3

  const int HW = H * W;
  const float* ib = in + (size_t)b * Cin * HW;
  const float* wb = w + (size_t)co * Cin * 9;

  const int iy0 = 2*y, iy1 = 2*y + 1, iy2 = 2*y + 2;
  const bool okB = (iy2 < H);
  const int iy2c = okB ? iy2 : 0;
  const int ix = 2 * x0;                 // input cols ix..ix+8
  const bool okR = (ix + 8 < W);
  const int ix8 = okR ? (ix + 8) : 0;

  float a0 = 0.f, a1 = 0.f, a2 = 0.f, a3 = 0.f;
  for (int ci = 0; ci < Cin; ++ci) {
    const float* p = ib + ci * HW;
    const float* wp = wb + ci * 9;
    #pragma unroll
    for (int dy = 0; dy < 3; ++dy) {
      const int ry = (dy == 0) ? iy0 : ((dy == 1) ? iy1 : iy2c);
      const float* r = p + ry * W;
      float v0 = r[ix],   v1 = r[ix+1], v2 = r[ix+2], v3 = r[ix+3];
      float v4 = r[ix+4], v5 = r[ix+5], v6 = r[ix+6], v7 = r[ix+7];
      float v8 = r[ix8];  v8 = okR ? v8 : 0.f;
      if (dy == 2 && !okB) { v0=0.f;v1=0.f;v2=0.f;v3=0.f;v4=0.f;v5=0.f;v6=0.f;v7=0.f;v8=0.f; }
      const float wa = wp[dy*3], wm = wp[dy*3+1], wc = wp[dy*3+2];
      a0 += v0*wa + v1*wm + v2*wc;
      a1 += v2*wa + v3*wm + v4*wc;
      a2 += v4*wa + v5*wm + v6*wc;
      a3 += v6*wa + v7*wm + v8*wc;
    }
  }
  const float bv = bias[co];
  float4 r4;
  r4.x = act_fn<ACT>(a0 + bv);
  r4.y = act_fn<ACT>(a1 + bv);
  r4.z = act_fn<ACT>(a2 + bv);
  r4.w = act_fn<ACT>(a3 + bv);
  float* op = out + (size_t)plane * (Ho * Wo) + y * Wo + x0;
  *(float4*)op = r4;
}

// ---------------- stride-2 3x3 SAME transposed conv ----------------------------
// jax.lax.conv_transpose SAME, k=3, s=2: lhs_dilation=2, pad=(2,1), no kernel flip.
// out[2i,2j]     = sum ci: x[i-1,j-1]w00 + x[i-1,j]w02 + x[i,j-1]w20 + x[i,j]w22
// out[2i,2j+1]   = sum ci: x[i-1,j]w01 + x[i,j]w21
// out[2i+1,2j]   = sum ci: x[i,j-1]w10 + x[i,j]w12
// out[2i+1,2j+1] = sum ci: x[i,j]w11
// Each thread computes one 2x2 output block at (i,j).
template<int ACT>
__global__ __launch_bounds__(256)
void tconv3x3(const float* __restrict__ in, const float* __restrict__ w,
              const float* __restrict__ bias, float* __restrict__ out,
              int Cin, int Cout, int Hin) {
  const int plane = blockIdx.x;            // b*Cout + co
  const int co = plane % Cout;
  const int b  = plane / Cout;
  const int items = Hin * Hin;
  const int item = blockIdx.y * 256 + threadIdx.x;
  if (item >= items) return;
  const int i = item / Hin;
  const int j = item - i * Hin;

  const float* ib = in + (size_t)b * Cin * items;
  const float* wb = w + (size_t)co * Cin * 9;
  const bool okT = (i > 0), okL = (j > 0);
  const int im = okT ? i - 1 : 0;
  const int jm = okL ? j - 1 : 0;

  float a00 = 0.f, a01 = 0.f, a10 = 0.f, a11 = 0.f;
  for (int ci = 0; ci < Cin; ++ci) {
    const float* p = ib + ci * items;
    float xtl = p[im*Hin + jm]; xtl = (okT && okL) ? xtl : 0.f;
    float xtr = p[im*Hin + j];  xtr = okT ? xtr : 0.f;
    float xbl = p[i*Hin + jm];  xbl = okL ? xbl : 0.f;
    float xbr = p[i*Hin + j];
    const float* wp = wb + ci * 9;
    const float w00 = wp[0], w01 = wp[1], w02 = wp[2];
    const float w10 = wp[3], w11 = wp[4], w12 = wp[5];
    const float w20 = wp[6], w21 = wp[7], w22 = wp[8];
    a00 += xtl*w00 + xtr*w02 + xbl*w20 + xbr*w22;
    a01 += xtr*w01 + xbr*w21;
    a10 += xbl*w10 + xbr*w12;
    a11 += xbr*w11;
  }
  const float bv = bias[co];
  a00 = act_fn<ACT>(a00 + bv);
  a01 = act_fn<ACT>(a01 + bv);
  a10 = act_fn<ACT>(a10 + bv);
  a11 = act_fn<ACT>(a11 + bv);
  const int Ho = Hin * 2;
  float* op = out + (size_t)plane * Ho * Ho + (2*i) * Ho + 2*j;
  float2 t0; t0.x = a00; t0.y = a01;
  float2 t1; t1.x = a10; t1.y = a11;
  *(float2*)op = t0;
  *(float2*)(op + Ho) = t1;
}

// ---------------- keypoint reductions: S = sum R, Sh = sum R*h, Sw = sum R*w ----
__global__ __launch_bounds__(64)
void kp_reduce(const float* __restrict__ R, float* __restrict__ S,
               float* __restrict__ Sh, float* __restrict__ Sw) {
  const int bk = blockIdx.x;       // b*K + k, 16x16 maps
  const int t = threadIdx.x;       // 64
  const float* p = R + (size_t)bk * 256;
  float s = 0.f, sh = 0.f, sw = 0.f;
  #pragma unroll
  for (int q = 0; q < 4; ++q) {
    int idx = t + q * 64;
    float v = p[idx];
    s  += v;
    sh += v * (float)(idx >> 4);
    sw += v * (float)(idx & 15);
  }
  #pragma unroll
  for (int off = 32; off > 0; off >>= 1) {
    s  += __shfl_down(s, off);
    sh += __shfl_down(sh, off);
    sw += __shfl_down(sw, off);
  }
  if (t == 0) { S[bk] = s; Sh[bk] = sh; Sw[bk] = sw; }
}

// ---------------- gaussian blob maps -------------------------------------------
__global__ __launch_bounds__(256)
void kp_maps(const float* __restrict__ S, const float* __restrict__ Sh,
             const float* __restrict__ Sw, float* __restrict__ maps, int K) {
  const int bk = blockIdx.x;
  const int b = bk / K;
  const int t = threadIdx.x;       // 256 = 16x16
  const float s   = S[bk];
  const float den = S[b * K + (K - 1)];
  const float mu  = s * (1.0f / 256.0f);
  const float c0  = Sh[bk] / den;
  const float c1  = Sw[bk] / den;
  const float u = (float)(t >> 4);
  const float v = (float)(t & 15);
  const float d2 = (u - c0) * (u - c0) + (v - c1) * (v - c1);
  maps[(size_t)bk * 256 + t] = mu * expf(-0.5f * d2);
}

extern "C" void kernel_launch(void* const* d_in, const int* in_sizes, int n_in,
                              void* d_out, int out_size, void* d_ws, size_t ws_size,
                              hipStream_t stream) {
  const int B = 32;  // 4 * 8
  const float* x = (const float*)d_in[0];
  const float* ew[7]; const float* eb[7];
  for (int j = 0; j < 7; ++j) { ew[j] = (const float*)d_in[1 + 2*j]; eb[j] = (const float*)d_in[2 + 2*j]; }
  const float* dw[6]; const float* db[6];
  for (int j = 0; j < 6; ++j) { dw[j] = (const float*)d_in[15 + 2*j]; db[j] = (const float*)d_in[16 + 2*j]; }

  float* ws   = (float*)d_ws;
  float* bufA = ws;                       // 32*32*128*128 = 16,777,216 floats
  float* bufB = bufA + 16777216;          // same
  float* R    = bufB + 16777216;          // 32*128*256 = 1,048,576
  float* maps = R + 1048576;              // 1,048,576
  float* S    = maps + 1048576;           // 4096
  float* Sh   = S + 4096;                 // 4096
  float* Sw   = Sh + 4096;                // 4096
  float* outp = (float*)d_out;            // 32*16*128*128

  dim3 blk(256);

  // ---- encoder ----
  conv3x3_s1<ACT_ID>      <<<dim3(B*32, 16), blk, 0, stream>>>(x,    ew[0], eb[0], bufA, 3,   32,  128, 128);
  conv3x3_s1<ACT_ID>      <<<dim3(B*32, 16), blk, 0, stream>>>(bufA, ew[1], eb[1], bufB, 32,  32,  128, 128);
  conv3x3_s2<ACT_LRELU>   <<<dim3(B*64, 4),  blk, 0, stream>>>(bufB, ew[2], eb[2], bufA, 32,  64,  128, 128);
  conv3x3_s1<ACT_LRELU>   <<<dim3(B*64, 4),  blk, 0, stream>>>(bufA, ew[3], eb[3], bufB, 64,  64,  64,  64);
  conv3x3_s2<ACT_LRELU>   <<<dim3(B*128, 1), blk, 0, stream>>>(bufB, ew[4], eb[4], bufA, 64,  128, 64,  64);
  conv3x3_s1<ACT_LRELU>   <<<dim3(B*128, 1), blk, 0, stream>>>(bufA, ew[5], eb[5], bufB, 128, 128, 32,  32);
  conv3x3_s2<ACT_SOFTPLUS><<<dim3(B*128, 1), blk, 0, stream>>>(bufB, ew[6], eb[6], R,    128, 128, 32,  32);

  // ---- keypoint bottleneck ----
  kp_reduce<<<dim3(B*128), dim3(64), 0, stream>>>(R, S, Sh, Sw);
  kp_maps  <<<dim3(B*128), blk, 0, stream>>>(S, Sh, Sw, maps, 128);

  // ---- decoder ----
  tconv3x3<ACT_RELU>  <<<dim3(B*64, 1),  blk, 0, stream>>>(maps, dw[0], db[0], bufA, 128, 64, 16);
  conv3x3_s1<ACT_RELU><<<dim3(B*64, 1),  blk, 0, stream>>>(bufA, dw[1], db[1], bufB, 64,  64, 32, 32);
  tconv3x3<ACT_RELU>  <<<dim3(B*32, 4),  blk, 0, stream>>>(bufB, dw[2], db[2], bufA, 64,  32, 32);
  conv3x3_s1<ACT_RELU><<<dim3(B*32, 4),  blk, 0, stream>>>(bufA, dw[3], db[3], bufB, 32,  32, 64, 64);
  tconv3x3<ACT_RELU>  <<<dim3(B*16, 16), blk, 0, stream>>>(bufB, dw[4], db[4], bufA, 32,  16, 64);
  conv3x3_s1<ACT_RELU><<<dim3(B*16, 16), blk, 0, stream>>>(bufA, dw[5], db[5], outp, 16,  16, 128, 128);
}

// Round 2
// 1374.750 us; speedup vs baseline: 3.5083x; 3.5083x over previous
//
#include <hip/hip_runtime.h>
#include <math.h>

// ULOSD keypoint autoencoder, fp32 direct convolutions, multi-cout per thread.
// Key idea: each thread accumulates NC=8 output channels for CPT output pixels.
// The channel group is blockIdx-derived (wave-uniform) so all weight/bias reads
// compile to scalar s_loads (SMEM pipe) -> per ci: 18 vector loads feed 288 FMAs.

enum { ACT_ID = 0, ACT_LRELU = 1, ACT_SOFTPLUS = 2, ACT_RELU = 3 };

template<int ACT>
__device__ __forceinline__ float act_fn(float x) {
  if (ACT == ACT_LRELU)    return x >= 0.f ? x : 0.2f * x;
  if (ACT == ACT_SOFTPLUS) return fmaxf(x, 0.f) + log1pf(expf(-fabsf(x)));
  if (ACT == ACT_RELU)     return fmaxf(x, 0.f);
  return x;
}

// ---------------- stride-1 3x3 SAME conv, NC couts x CPT cols per thread -------
template<int ACT, int NC, int CPT>
__global__ __launch_bounds__(256)
void conv_s1(const float* __restrict__ in, const float* __restrict__ w,
             const float* __restrict__ bias, float* __restrict__ out,
             int Cin, int Cout, int H, int W) {
  const int cogs = Cout / NC;
  const int gx  = blockIdx.x;           // b*cogs + cog
  const int cog = gx % cogs;
  const int b   = gx / cogs;
  const int co0 = cog * NC;
  const int Wq  = W / CPT;
  const int items = H * Wq;
  const int item  = blockIdx.y * 256 + threadIdx.x;
  if (item >= items) return;
  const int y  = item / Wq;
  const int x0 = (item - y * Wq) * CPT;

  const int HW = H * W;
  const float* ib = in + (size_t)b * Cin * HW;

  const bool okT = (y > 0), okB = (y < H - 1);
  const bool okL = (x0 > 0), okR = (x0 + CPT < W);
  const int ym = okT ? (y - 1) : 0;
  const int yp = okB ? (y + 1) : 0;
  const int xl = okL ? (x0 - 1) : 0;
  const int xr = okR ? (x0 + CPT) : 0;

  float acc[NC][CPT];
  #pragma unroll
  for (int u = 0; u < NC; ++u)
    #pragma unroll
    for (int q = 0; q < CPT; ++q) acc[u][q] = 0.f;

  for (int ci = 0; ci < Cin; ++ci) {
    const float* p = ib + ci * HW;
    const float* wci = w + ((size_t)co0 * Cin + ci) * 9;  // +u*Cin*9 per channel
    #pragma unroll
    for (int dy = 0; dy < 3; ++dy) {
      const int  ry    = (dy == 0) ? ym : ((dy == 1) ? y : yp);
      const bool okRow = (dy == 0) ? okT : ((dy == 1) ? true : okB);
      const float* r = p + ry * W;
      float v[CPT + 2];
      if (CPT == 4) {
        float  lf = r[xl];
        float4 m  = *(const float4*)(r + x0);
        float  rf = r[xr];
        v[0] = (okRow && okL) ? lf : 0.f;
        v[1] = okRow ? m.x : 0.f;
        v[2] = okRow ? m.y : 0.f;
        v[3] = okRow ? m.z : 0.f;
        v[4] = okRow ? m.w : 0.f;
        v[5] = (okRow && okR) ? rf : 0.f;
      } else {
        v[0] = (okRow && okL) ? r[xl] : 0.f;
        #pragma unroll
        for (int q = 0; q < CPT; ++q) v[1 + q] = okRow ? r[x0 + q] : 0.f;
        v[CPT + 1] = (okRow && okR) ? r[xr] : 0.f;
      }
      #pragma unroll
      for (int u = 0; u < NC; ++u) {
        const float* wp = wci + (size_t)u * Cin * 9 + dy * 3;
        const float w0 = wp[0], w1 = wp[1], w2 = wp[2];
        #pragma unroll
        for (int q = 0; q < CPT; ++q)
          acc[u][q] += v[q] * w0 + v[q + 1] * w1 + v[q + 2] * w2;
      }
    }
  }

  #pragma unroll
  for (int u = 0; u < NC; ++u) {
    const float bv = bias[co0 + u];
    float* op = out + ((size_t)(b * Cout + co0 + u) * H + y) * W + x0;
    if (CPT == 4) {
      float4 r4;
      r4.x = act_fn<ACT>(acc[u][0] + bv);
      r4.y = act_fn<ACT>(acc[u][1] + bv);
      r4.z = act_fn<ACT>(acc[u][2] + bv);
      r4.w = act_fn<ACT>(acc[u][3] + bv);
      *(float4*)op = r4;
    } else {
      #pragma unroll
      for (int q = 0; q < CPT; ++q) op[q] = act_fn<ACT>(acc[u][q] + bv);
    }
  }
}

// ---------------- stride-2 3x3 SAME conv (pad_before=0, pad_after=1) -----------
template<int ACT, int NC, int CPT>
__global__ __launch_bounds__(256)
void conv_s2(const float* __restrict__ in, const float* __restrict__ w,
             const float* __restrict__ bias, float* __restrict__ out,
             int Cin, int Cout, int H, int W) {
  const int Ho = H >> 1, Wo = W >> 1;
  const int cogs = Cout / NC;
  const int gx  = blockIdx.x;
  const int cog = gx % cogs;
  const int b   = gx / cogs;
  const int co0 = cog * NC;
  const int Wq  = Wo / CPT;
  const int items = Ho * Wq;
  const int item  = blockIdx.y * 256 + threadIdx.x;
  if (item >= items) return;
  const int y  = item / Wq;
  const int x0 = (item - y * Wq) * CPT;
  const int ix = 2 * x0;                     // input cols ix .. ix+2*CPT

  const int HW = H * W;
  const float* ib = in + (size_t)b * Cin * HW;

  const int iy0 = 2 * y, iy1 = 2 * y + 1, iy2 = 2 * y + 2;
  const bool okB = (iy2 < H);
  const int iy2c = okB ? iy2 : 0;
  const bool okR = (ix + 2 * CPT < W);
  const int ixr  = okR ? (ix + 2 * CPT) : 0;

  float acc[NC][CPT];
  #pragma unroll
  for (int u = 0; u < NC; ++u)
    #pragma unroll
    for (int q = 0; q < CPT; ++q) acc[u][q] = 0.f;

  for (int ci = 0; ci < Cin; ++ci) {
    const float* p = ib + ci * HW;
    const float* wci = w + ((size_t)co0 * Cin + ci) * 9;
    #pragma unroll
    for (int dy = 0; dy < 3; ++dy) {
      const int  ry    = (dy == 0) ? iy0 : ((dy == 1) ? iy1 : iy2c);
      const bool okRow = (dy < 2) || okB;
      const float* r = p + ry * W;
      float v[2 * CPT + 1];
      if (CPT == 4) {
        float4 m0 = *(const float4*)(r + ix);
        float4 m1 = *(const float4*)(r + ix + 4);
        float  rf = r[ixr];
        v[0] = okRow ? m0.x : 0.f; v[1] = okRow ? m0.y : 0.f;
        v[2] = okRow ? m0.z : 0.f; v[3] = okRow ? m0.w : 0.f;
        v[4] = okRow ? m1.x : 0.f; v[5] = okRow ? m1.y : 0.f;
        v[6] = okRow ? m1.z : 0.f; v[7] = okRow ? m1.w : 0.f;
        v[8] = (okRow && okR) ? rf : 0.f;
      } else {
        #pragma unroll
        for (int q = 0; q < 2 * CPT; ++q) v[q] = okRow ? r[ix + q] : 0.f;
        v[2 * CPT] = (okRow && okR) ? r[ixr] : 0.f;
      }
      #pragma unroll
      for (int u = 0; u < NC; ++u) {
        const float* wp = wci + (size_t)u * Cin * 9 + dy * 3;
        const float w0 = wp[0], w1 = wp[1], w2 = wp[2];
        #pragma unroll
        for (int q = 0; q < CPT; ++q)
          acc[u][q] += v[2*q] * w0 + v[2*q + 1] * w1 + v[2*q + 2] * w2;
      }
    }
  }

  #pragma unroll
  for (int u = 0; u < NC; ++u) {
    const float bv = bias[co0 + u];
    float* op = out + ((size_t)(b * Cout + co0 + u) * Ho + y) * Wo + x0;
    if (CPT == 4) {
      float4 r4;
      r4.x = act_fn<ACT>(acc[u][0] + bv);
      r4.y = act_fn<ACT>(acc[u][1] + bv);
      r4.z = act_fn<ACT>(acc[u][2] + bv);
      r4.w = act_fn<ACT>(acc[u][3] + bv);
      *(float4*)op = r4;
    } else {
      #pragma unroll
      for (int q = 0; q < CPT; ++q) op[q] = act_fn<ACT>(acc[u][q] + bv);
    }
  }
}

// ---------------- stride-2 3x3 SAME transposed conv ----------------------------
// out[2i,2j]=xtl*w00+xtr*w02+xbl*w20+xbr*w22; out[2i,2j+1]=xtr*w01+xbr*w21
// out[2i+1,2j]=xbl*w10+xbr*w12;               out[2i+1,2j+1]=xbr*w11
template<int ACT, int NC>
__global__ __launch_bounds__(256)
void tconv(const float* __restrict__ in, const float* __restrict__ w,
           const float* __restrict__ bias, float* __restrict__ out,
           int Cin, int Cout, int Hin) {
  const int cogs = Cout / NC;
  const int gx  = blockIdx.x;
  const int cog = gx % cogs;
  const int b   = gx / cogs;
  const int co0 = cog * NC;
  const int items = Hin * Hin;
  const int item  = blockIdx.y * 256 + threadIdx.x;
  if (item >= items) return;
  const int i = item / Hin;
  const int j = item - i * Hin;

  const float* ib = in + (size_t)b * Cin * items;
  const bool okT = (i > 0), okL = (j > 0);
  const int im = okT ? i - 1 : 0;
  const int jm = okL ? j - 1 : 0;

  float a00[NC], a01[NC], a10[NC], a11[NC];
  #pragma unroll
  for (int u = 0; u < NC; ++u) { a00[u]=0.f; a01[u]=0.f; a10[u]=0.f; a11[u]=0.f; }

  for (int ci = 0; ci < Cin; ++ci) {
    const float* p = ib + ci * items;
    float xtl = p[im*Hin + jm]; xtl = (okT && okL) ? xtl : 0.f;
    float xtr = p[im*Hin + j];  xtr = okT ? xtr : 0.f;
    float xbl = p[i*Hin + jm];  xbl = okL ? xbl : 0.f;
    float xbr = p[i*Hin + j];
    const float* wci = w + ((size_t)co0 * Cin + ci) * 9;
    #pragma unroll
    for (int u = 0; u < NC; ++u) {
      const float* wp = wci + (size_t)u * Cin * 9;
      const float w00 = wp[0], w01 = wp[1], w02 = wp[2];
      const float w10 = wp[3], w11 = wp[4], w12 = wp[5];
      const float w20 = wp[6], w21 = wp[7], w22 = wp[8];
      a00[u] += xtl*w00 + xtr*w02 + xbl*w20 + xbr*w22;
      a01[u] += xtr*w01 + xbr*w21;
      a10[u] += xbl*w10 + xbr*w12;
      a11[u] += xbr*w11;
    }
  }

  const int Ho = Hin * 2;
  #pragma unroll
  for (int u = 0; u < NC; ++u) {
    const float bv = bias[co0 + u];
    float* op = out + (size_t)(b * Cout + co0 + u) * Ho * Ho + (2*i) * Ho + 2*j;
    float2 t0, t1;
    t0.x = act_fn<ACT>(a00[u] + bv); t0.y = act_fn<ACT>(a01[u] + bv);
    t1.x = act_fn<ACT>(a10[u] + bv); t1.y = act_fn<ACT>(a11[u] + bv);
    *(float2*)op = t0;
    *(float2*)(op + Ho) = t1;
  }
}

// ---------------- keypoint reductions: S = sum R, Sh = sum R*h, Sw = sum R*w ----
__global__ __launch_bounds__(64)
void kp_reduce(const float* __restrict__ R, float* __restrict__ S,
               float* __restrict__ Sh, float* __restrict__ Sw) {
  const int bk = blockIdx.x;       // b*K + k, 16x16 maps
  const int t = threadIdx.x;       // 64
  const float* p = R + (size_t)bk * 256;
  float s = 0.f, sh = 0.f, sw = 0.f;
  #pragma unroll
  for (int q = 0; q < 4; ++q) {
    int idx = t + q * 64;
    float v = p[idx];
    s  += v;
    sh += v * (float)(idx >> 4);
    sw += v * (float)(idx & 15);
  }
  #pragma unroll
  for (int off = 32; off > 0; off >>= 1) {
    s  += __shfl_down(s, off);
    sh += __shfl_down(sh, off);
    sw += __shfl_down(sw, off);
  }
  if (t == 0) { S[bk] = s; Sh[bk] = sh; Sw[bk] = sw; }
}

// ---------------- gaussian blob maps -------------------------------------------
__global__ __launch_bounds__(256)
void kp_maps(const float* __restrict__ S, const float* __restrict__ Sh,
             const float* __restrict__ Sw, float* __restrict__ maps, int K) {
  const int bk = blockIdx.x;
  const int b = bk / K;
  const int t = threadIdx.x;       // 256 = 16x16
  const float s   = S[bk];
  const float den = S[b * K + (K - 1)];
  const float mu  = s * (1.0f / 256.0f);
  const float c0  = Sh[bk] / den;
  const float c1  = Sw[bk] / den;
  const float u = (float)(t >> 4);
  const float v = (float)(t & 15);
  const float d2 = (u - c0) * (u - c0) + (v - c1) * (v - c1);
  maps[(size_t)bk * 256 + t] = mu * expf(-0.5f * d2);
}

extern "C" void kernel_launch(void* const* d_in, const int* in_sizes, int n_in,
                              void* d_out, int out_size, void* d_ws, size_t ws_size,
                              hipStream_t stream) {
  const int B = 32;  // 4 * 8
  const float* x = (const float*)d_in[0];
  const float* ew[7]; const float* eb[7];
  for (int j = 0; j < 7; ++j) { ew[j] = (const float*)d_in[1 + 2*j]; eb[j] = (const float*)d_in[2 + 2*j]; }
  const float* dw[6]; const float* db[6];
  for (int j = 0; j < 6; ++j) { dw[j] = (const float*)d_in[15 + 2*j]; db[j] = (const float*)d_in[16 + 2*j]; }

  float* ws   = (float*)d_ws;
  float* bufA = ws;                       // 32*32*128*128 = 16,777,216 floats
  float* bufB = bufA + 16777216;
  float* R    = bufB + 16777216;          // 32*128*256 = 1,048,576
  float* maps = R + 1048576;
  float* S    = maps + 1048576;           // 4096
  float* Sh   = S + 4096;
  float* Sw   = Sh + 4096;
  float* outp = (float*)d_out;            // 32*16*128*128

  dim3 blk(256);

  // ---- encoder ----
  // grid.x = B * (Cout/NC), grid.y = ceil(H*W/CPT / 256)
  conv_s1<ACT_ID,      8,4><<<dim3(B*4,  16), blk, 0, stream>>>(x,    ew[0], eb[0], bufA, 3,   32,  128, 128);
  conv_s1<ACT_ID,      8,4><<<dim3(B*4,  16), blk, 0, stream>>>(bufA, ew[1], eb[1], bufB, 32,  32,  128, 128);
  conv_s2<ACT_LRELU,   8,4><<<dim3(B*8,   4), blk, 0, stream>>>(bufB, ew[2], eb[2], bufA, 32,  64,  128, 128);
  conv_s1<ACT_LRELU,   8,4><<<dim3(B*8,   4), blk, 0, stream>>>(bufA, ew[3], eb[3], bufB, 64,  64,  64,  64);
  conv_s2<ACT_LRELU,   8,4><<<dim3(B*16,  1), blk, 0, stream>>>(bufB, ew[4], eb[4], bufA, 64,  128, 64,  64);
  conv_s1<ACT_LRELU,   8,4><<<dim3(B*16,  1), blk, 0, stream>>>(bufA, ew[5], eb[5], bufB, 128, 128, 32,  32);
  conv_s2<ACT_SOFTPLUS,8,1><<<dim3(B*16,  1), blk, 0, stream>>>(bufB, ew[6], eb[6], R,    128, 128, 32,  32);

  // ---- keypoint bottleneck ----
  kp_reduce<<<dim3(B*128), dim3(64), 0, stream>>>(R, S, Sh, Sw);
  kp_maps  <<<dim3(B*128), blk, 0, stream>>>(S, Sh, Sw, maps, 128);

  // ---- decoder ----
  tconv<ACT_RELU,   8>  <<<dim3(B*8,   1), blk, 0, stream>>>(maps, dw[0], db[0], bufA, 128, 64, 16);
  conv_s1<ACT_RELU, 8,4><<<dim3(B*8,   1), blk, 0, stream>>>(bufA, dw[1], db[1], bufB, 64,  64, 32, 32);
  tconv<ACT_RELU,   8>  <<<dim3(B*4,   4), blk, 0, stream>>>(bufB, dw[2], db[2], bufA, 64,  32, 32);
  conv_s1<ACT_RELU, 8,4><<<dim3(B*4,   4), blk, 0, stream>>>(bufA, dw[3], db[3], bufB, 32,  32, 64, 64);
  tconv<ACT_RELU,   8>  <<<dim3(B*2,  16), blk, 0, stream>>>(bufB, dw[4], db[4], bufA, 32,  16, 64);
  conv_s1<ACT_RELU, 8,4><<<dim3(B*2,  16), blk, 0, stream>>>(bufA, dw[5], db[5], outp, 16,  16, 128, 128);
}

// Round 3
// 1281.037 us; speedup vs baseline: 3.7649x; 1.0732x over previous
//
#include <hip/hip_runtime.h>
#include <math.h>

// ULOSD keypoint autoencoder, fp32 direct convolutions, multi-cout per thread.
// Round 3: per-layer (NC, CPT) retuned so every dispatch launches >=1024 blocks
// (>=16 waves/CU) -- round-2 counters showed 20% occupancy / latency-bound on
// all spatial<=32 layers. Weight reads stay wave-uniform (scalar s_loads).

enum { ACT_ID = 0, ACT_LRELU = 1, ACT_SOFTPLUS = 2, ACT_RELU = 3 };

template<int ACT>
__device__ __forceinline__ float act_fn(float x) {
  if (ACT == ACT_LRELU)    return x >= 0.f ? x : 0.2f * x;
  if (ACT == ACT_SOFTPLUS) return fmaxf(x, 0.f) + log1pf(expf(-fabsf(x)));
  if (ACT == ACT_RELU)     return fmaxf(x, 0.f);
  return x;
}

// ---------------- stride-1 3x3 SAME conv, NC couts x CPT cols per thread -------
template<int ACT, int NC, int CPT>
__global__ __launch_bounds__(256)
void conv_s1(const float* __restrict__ in, const float* __restrict__ w,
             const float* __restrict__ bias, float* __restrict__ out,
             int Cin, int Cout, int H, int W) {
  const int cogs = Cout / NC;
  const int gx  = blockIdx.x;           // b*cogs + cog
  const int cog = gx % cogs;
  const int b   = gx / cogs;
  const int co0 = cog * NC;
  const int Wq  = W / CPT;
  const int items = H * Wq;
  const int item  = blockIdx.y * 256 + threadIdx.x;
  if (item >= items) return;
  const int y  = item / Wq;
  const int x0 = (item - y * Wq) * CPT;

  const int HW = H * W;
  const float* ib = in + (size_t)b * Cin * HW;

  const bool okT = (y > 0), okB = (y < H - 1);
  const bool okL = (x0 > 0), okR = (x0 + CPT < W);
  const int ym = okT ? (y - 1) : 0;
  const int yp = okB ? (y + 1) : 0;
  const int xl = okL ? (x0 - 1) : 0;
  const int xr = okR ? (x0 + CPT) : 0;

  float acc[NC][CPT];
  #pragma unroll
  for (int u = 0; u < NC; ++u)
    #pragma unroll
    for (int q = 0; q < CPT; ++q) acc[u][q] = 0.f;

  for (int ci = 0; ci < Cin; ++ci) {
    const float* p = ib + ci * HW;
    const float* wci = w + ((size_t)co0 * Cin + ci) * 9;  // +u*Cin*9 per channel
    #pragma unroll
    for (int dy = 0; dy < 3; ++dy) {
      const int  ry    = (dy == 0) ? ym : ((dy == 1) ? y : yp);
      const bool okRow = (dy == 0) ? okT : ((dy == 1) ? true : okB);
      const float* r = p + ry * W;
      float v[CPT + 2];
      if (CPT == 4) {
        float  lf = r[xl];
        float4 m  = *(const float4*)(r + x0);
        float  rf = r[xr];
        v[0] = (okRow && okL) ? lf : 0.f;
        v[1] = okRow ? m.x : 0.f;
        v[2] = okRow ? m.y : 0.f;
        v[3] = okRow ? m.z : 0.f;
        v[4] = okRow ? m.w : 0.f;
        v[5] = (okRow && okR) ? rf : 0.f;
      } else if (CPT == 2) {
        float  lf = r[xl];
        float2 m  = *(const float2*)(r + x0);   // x0 even -> aligned
        float  rf = r[xr];
        v[0] = (okRow && okL) ? lf : 0.f;
        v[1] = okRow ? m.x : 0.f;
        v[2] = okRow ? m.y : 0.f;
        v[3] = (okRow && okR) ? rf : 0.f;
      } else {
        v[0] = (okRow && okL) ? r[xl] : 0.f;
        #pragma unroll
        for (int q = 0; q < CPT; ++q) v[1 + q] = okRow ? r[x0 + q] : 0.f;
        v[CPT + 1] = (okRow && okR) ? r[xr] : 0.f;
      }
      #pragma unroll
      for (int u = 0; u < NC; ++u) {
        const float* wp = wci + (size_t)u * Cin * 9 + dy * 3;
        const float w0 = wp[0], w1 = wp[1], w2 = wp[2];
        #pragma unroll
        for (int q = 0; q < CPT; ++q)
          acc[u][q] += v[q] * w0 + v[q + 1] * w1 + v[q + 2] * w2;
      }
    }
  }

  #pragma unroll
  for (int u = 0; u < NC; ++u) {
    const float bv = bias[co0 + u];
    float* op = out + ((size_t)(b * Cout + co0 + u) * H + y) * W + x0;
    if (CPT == 4) {
      float4 r4;
      r4.x = act_fn<ACT>(acc[u][0] + bv);
      r4.y = act_fn<ACT>(acc[u][1] + bv);
      r4.z = act_fn<ACT>(acc[u][2] + bv);
      r4.w = act_fn<ACT>(acc[u][3] + bv);
      *(float4*)op = r4;
    } else if (CPT == 2) {
      float2 r2;
      r2.x = act_fn<ACT>(acc[u][0] + bv);
      r2.y = act_fn<ACT>(acc[u][1] + bv);
      *(float2*)op = r2;
    } else {
      #pragma unroll
      for (int q = 0; q < CPT; ++q) op[q] = act_fn<ACT>(acc[u][q] + bv);
    }
  }
}

// ---------------- stride-2 3x3 SAME conv (pad_before=0, pad_after=1) -----------
template<int ACT, int NC, int CPT>
__global__ __launch_bounds__(256)
void conv_s2(const float* __restrict__ in, const float* __restrict__ w,
             const float* __restrict__ bias, float* __restrict__ out,
             int Cin, int Cout, int H, int W) {
  const int Ho = H >> 1, Wo = W >> 1;
  const int cogs = Cout / NC;
  const int gx  = blockIdx.x;
  const int cog = gx % cogs;
  const int b   = gx / cogs;
  const int co0 = cog * NC;
  const int Wq  = Wo / CPT;
  const int items = Ho * Wq;
  const int item  = blockIdx.y * 256 + threadIdx.x;
  if (item >= items) return;
  const int y  = item / Wq;
  const int x0 = (item - y * Wq) * CPT;
  const int ix = 2 * x0;                     // input cols ix .. ix+2*CPT

  const int HW = H * W;
  const float* ib = in + (size_t)b * Cin * HW;

  const int iy0 = 2 * y, iy1 = 2 * y + 1, iy2 = 2 * y + 2;
  const bool okB = (iy2 < H);
  const int iy2c = okB ? iy2 : 0;
  const bool okR = (ix + 2 * CPT < W);
  const int ixr  = okR ? (ix + 2 * CPT) : 0;

  float acc[NC][CPT];
  #pragma unroll
  for (int u = 0; u < NC; ++u)
    #pragma unroll
    for (int q = 0; q < CPT; ++q) acc[u][q] = 0.f;

  for (int ci = 0; ci < Cin; ++ci) {
    const float* p = ib + ci * HW;
    const float* wci = w + ((size_t)co0 * Cin + ci) * 9;
    #pragma unroll
    for (int dy = 0; dy < 3; ++dy) {
      const int  ry    = (dy == 0) ? iy0 : ((dy == 1) ? iy1 : iy2c);
      const bool okRow = (dy < 2) || okB;
      const float* r = p + ry * W;
      float v[2 * CPT + 1];
      if (CPT == 4) {
        float4 m0 = *(const float4*)(r + ix);
        float4 m1 = *(const float4*)(r + ix + 4);
        float  rf = r[ixr];
        v[0] = okRow ? m0.x : 0.f; v[1] = okRow ? m0.y : 0.f;
        v[2] = okRow ? m0.z : 0.f; v[3] = okRow ? m0.w : 0.f;
        v[4] = okRow ? m1.x : 0.f; v[5] = okRow ? m1.y : 0.f;
        v[6] = okRow ? m1.z : 0.f; v[7] = okRow ? m1.w : 0.f;
        v[8] = (okRow && okR) ? rf : 0.f;
      } else if (CPT == 2) {
        float4 m0 = *(const float4*)(r + ix);   // ix % 4 == 0 -> aligned
        float  rf = r[ixr];
        v[0] = okRow ? m0.x : 0.f; v[1] = okRow ? m0.y : 0.f;
        v[2] = okRow ? m0.z : 0.f; v[3] = okRow ? m0.w : 0.f;
        v[4] = (okRow && okR) ? rf : 0.f;
      } else if (CPT == 1) {
        float2 m0 = *(const float2*)(r + ix);   // ix even -> aligned
        float  rf = r[ixr];
        v[0] = okRow ? m0.x : 0.f; v[1] = okRow ? m0.y : 0.f;
        v[2] = (okRow && okR) ? rf : 0.f;
      } else {
        #pragma unroll
        for (int q = 0; q < 2 * CPT; ++q) v[q] = okRow ? r[ix + q] : 0.f;
        v[2 * CPT] = (okRow && okR) ? r[ixr] : 0.f;
      }
      #pragma unroll
      for (int u = 0; u < NC; ++u) {
        const float* wp = wci + (size_t)u * Cin * 9 + dy * 3;
        const float w0 = wp[0], w1 = wp[1], w2 = wp[2];
        #pragma unroll
        for (int q = 0; q < CPT; ++q)
          acc[u][q] += v[2*q] * w0 + v[2*q + 1] * w1 + v[2*q + 2] * w2;
      }
    }
  }

  #pragma unroll
  for (int u = 0; u < NC; ++u) {
    const float bv = bias[co0 + u];
    float* op = out + ((size_t)(b * Cout + co0 + u) * Ho + y) * Wo + x0;
    if (CPT == 4) {
      float4 r4;
      r4.x = act_fn<ACT>(acc[u][0] + bv);
      r4.y = act_fn<ACT>(acc[u][1] + bv);
      r4.z = act_fn<ACT>(acc[u][2] + bv);
      r4.w = act_fn<ACT>(acc[u][3] + bv);
      *(float4*)op = r4;
    } else if (CPT == 2) {
      float2 r2;
      r2.x = act_fn<ACT>(acc[u][0] + bv);
      r2.y = act_fn<ACT>(acc[u][1] + bv);
      *(float2*)op = r2;
    } else {
      #pragma unroll
      for (int q = 0; q < CPT; ++q) op[q] = act_fn<ACT>(acc[u][q] + bv);
    }
  }
}

// ---------------- stride-2 3x3 SAME transposed conv ----------------------------
// out[2i,2j]=xtl*w00+xtr*w02+xbl*w20+xbr*w22; out[2i,2j+1]=xtr*w01+xbr*w21
// out[2i+1,2j]=xbl*w10+xbr*w12;               out[2i+1,2j+1]=xbr*w11
template<int ACT, int NC>
__global__ __launch_bounds__(256)
void tconv(const float* __restrict__ in, const float* __restrict__ w,
           const float* __restrict__ bias, float* __restrict__ out,
           int Cin, int Cout, int Hin) {
  const int cogs = Cout / NC;
  const int gx  = blockIdx.x;
  const int cog = gx % cogs;
  const int b   = gx / cogs;
  const int co0 = cog * NC;
  const int items = Hin * Hin;
  const int item  = blockIdx.y * 256 + threadIdx.x;
  if (item >= items) return;
  const int i = item / Hin;
  const int j = item - i * Hin;

  const float* ib = in + (size_t)b * Cin * items;
  const bool okT = (i > 0), okL = (j > 0);
  const int im = okT ? i - 1 : 0;
  const int jm = okL ? j - 1 : 0;

  float a00[NC], a01[NC], a10[NC], a11[NC];
  #pragma unroll
  for (int u = 0; u < NC; ++u) { a00[u]=0.f; a01[u]=0.f; a10[u]=0.f; a11[u]=0.f; }

  for (int ci = 0; ci < Cin; ++ci) {
    const float* p = ib + ci * items;
    float xtl = p[im*Hin + jm]; xtl = (okT && okL) ? xtl : 0.f;
    float xtr = p[im*Hin + j];  xtr = okT ? xtr : 0.f;
    float xbl = p[i*Hin + jm];  xbl = okL ? xbl : 0.f;
    float xbr = p[i*Hin + j];
    const float* wci = w + ((size_t)co0 * Cin + ci) * 9;
    #pragma unroll
    for (int u = 0; u < NC; ++u) {
      const float* wp = wci + (size_t)u * Cin * 9;
      const float w00 = wp[0], w01 = wp[1], w02 = wp[2];
      const float w10 = wp[3], w11 = wp[4], w12 = wp[5];
      const float w20 = wp[6], w21 = wp[7], w22 = wp[8];
      a00[u] += xtl*w00 + xtr*w02 + xbl*w20 + xbr*w22;
      a01[u] += xtr*w01 + xbr*w21;
      a10[u] += xbl*w10 + xbr*w12;
      a11[u] += xbr*w11;
    }
  }

  const int Ho = Hin * 2;
  #pragma unroll
  for (int u = 0; u < NC; ++u) {
    const float bv = bias[co0 + u];
    float* op = out + (size_t)(b * Cout + co0 + u) * Ho * Ho + (2*i) * Ho + 2*j;
    float2 t0, t1;
    t0.x = act_fn<ACT>(a00[u] + bv); t0.y = act_fn<ACT>(a01[u] + bv);
    t1.x = act_fn<ACT>(a10[u] + bv); t1.y = act_fn<ACT>(a11[u] + bv);
    *(float2*)op = t0;
    *(float2*)(op + Ho) = t1;
  }
}

// ---------------- keypoint reductions: S = sum R, Sh = sum R*h, Sw = sum R*w ----
__global__ __launch_bounds__(64)
void kp_reduce(const float* __restrict__ R, float* __restrict__ S,
               float* __restrict__ Sh, float* __restrict__ Sw) {
  const int bk = blockIdx.x;       // b*K + k, 16x16 maps
  const int t = threadIdx.x;       // 64
  const float* p = R + (size_t)bk * 256;
  float s = 0.f, sh = 0.f, sw = 0.f;
  #pragma unroll
  for (int q = 0; q < 4; ++q) {
    int idx = t + q * 64;
    float v = p[idx];
    s  += v;
    sh += v * (float)(idx >> 4);
    sw += v * (float)(idx & 15);
  }
  #pragma unroll
  for (int off = 32; off > 0; off >>= 1) {
    s  += __shfl_down(s, off);
    sh += __shfl_down(sh, off);
    sw += __shfl_down(sw, off);
  }
  if (t == 0) { S[bk] = s; Sh[bk] = sh; Sw[bk] = sw; }
}

// ---------------- gaussian blob maps -------------------------------------------
__global__ __launch_bounds__(256)
void kp_maps(const float* __restrict__ S, const float* __restrict__ Sh,
             const float* __restrict__ Sw, float* __restrict__ maps, int K) {
  const int bk = blockIdx.x;
  const int b = bk / K;
  const int t = threadIdx.x;       // 256 = 16x16
  const float s   = S[bk];
  const float den = S[b * K + (K - 1)];
  const float mu  = s * (1.0f / 256.0f);
  const float c0  = Sh[bk] / den;
  const float c1  = Sw[bk] / den;
  const float u = (float)(t >> 4);
  const float v = (float)(t & 15);
  const float d2 = (u - c0) * (u - c0) + (v - c1) * (v - c1);
  maps[(size_t)bk * 256 + t] = mu * expf(-0.5f * d2);
}

extern "C" void kernel_launch(void* const* d_in, const int* in_sizes, int n_in,
                              void* d_out, int out_size, void* d_ws, size_t ws_size,
                              hipStream_t stream) {
  const int B = 32;  // 4 * 8
  const float* x = (const float*)d_in[0];
  const float* ew[7]; const float* eb[7];
  for (int j = 0; j < 7; ++j) { ew[j] = (const float*)d_in[1 + 2*j]; eb[j] = (const float*)d_in[2 + 2*j]; }
  const float* dw[6]; const float* db[6];
  for (int j = 0; j < 6; ++j) { dw[j] = (const float*)d_in[15 + 2*j]; db[j] = (const float*)d_in[16 + 2*j]; }

  float* ws   = (float*)d_ws;
  float* bufA = ws;                       // 32*32*128*128 = 16,777,216 floats
  float* bufB = bufA + 16777216;
  float* R    = bufB + 16777216;          // 32*128*256 = 1,048,576
  float* maps = R + 1048576;
  float* S    = maps + 1048576;           // 4096
  float* Sh   = S + 4096;
  float* Sw   = Sh + 4096;
  float* outp = (float*)d_out;            // 32*16*128*128

  dim3 blk(256);

  // ---- encoder ----  grid.x = B*(Cout/NC), grid.y = ceil(H*W/CPT/256)
  conv_s1<ACT_ID,      8,4><<<dim3(B*4,  16), blk, 0, stream>>>(x,    ew[0], eb[0], bufA, 3,   32,  128, 128); // 2048 blk
  conv_s1<ACT_ID,      8,4><<<dim3(B*4,  16), blk, 0, stream>>>(bufA, ew[1], eb[1], bufB, 32,  32,  128, 128); // 2048 blk
  conv_s2<ACT_LRELU,   8,4><<<dim3(B*8,   4), blk, 0, stream>>>(bufB, ew[2], eb[2], bufA, 32,  64,  128, 128); // 1024 blk
  conv_s1<ACT_LRELU,   8,4><<<dim3(B*8,   4), blk, 0, stream>>>(bufA, ew[3], eb[3], bufB, 64,  64,  64,  64);  // 1024 blk
  conv_s2<ACT_LRELU,   8,2><<<dim3(B*16,  2), blk, 0, stream>>>(bufB, ew[4], eb[4], bufA, 64,  128, 64,  64);  // 1024 blk
  conv_s1<ACT_LRELU,   8,2><<<dim3(B*16,  2), blk, 0, stream>>>(bufA, ew[5], eb[5], bufB, 128, 128, 32,  32);  // 1024 blk
  conv_s2<ACT_SOFTPLUS,4,1><<<dim3(B*32,  1), blk, 0, stream>>>(bufB, ew[6], eb[6], R,    128, 128, 32,  32);  // 1024 blk

  // ---- keypoint bottleneck ----
  kp_reduce<<<dim3(B*128), dim3(64), 0, stream>>>(R, S, Sh, Sw);
  kp_maps  <<<dim3(B*128), blk, 0, stream>>>(S, Sh, Sw, maps, 128);

  // ---- decoder ----
  tconv<ACT_RELU,   2>  <<<dim3(B*32,  1), blk, 0, stream>>>(maps, dw[0], db[0], bufA, 128, 64, 16);           // 1024 blk
  conv_s1<ACT_RELU, 4,2><<<dim3(B*16,  2), blk, 0, stream>>>(bufA, dw[1], db[1], bufB, 64,  64, 32, 32);       // 1024 blk
  tconv<ACT_RELU,   4>  <<<dim3(B*8,   4), blk, 0, stream>>>(bufB, dw[2], db[2], bufA, 64,  32, 32);           // 1024 blk
  conv_s1<ACT_RELU, 8,2><<<dim3(B*4,   8), blk, 0, stream>>>(bufA, dw[3], db[3], bufB, 32,  32, 64, 64);       // 1024 blk
  tconv<ACT_RELU,   8>  <<<dim3(B*2,  16), blk, 0, stream>>>(bufB, dw[4], db[4], bufA, 32,  16, 64);           // 1024 blk
  conv_s1<ACT_RELU, 8,4><<<dim3(B*2,  16), blk, 0, stream>>>(bufA, dw[5], db[5], outp, 16,  16, 128, 128);     // 1024 blk
}